// Round 10
// baseline (284.428 us; speedup 1.0000x reference)
//
#include <hip/hip_runtime.h>
#include <stdint.h>

#define TT 512
#define BB 32
#define EE 512
#define HH 2048

typedef __attribute__((ext_vector_type(8))) short short8;   // 8 x bf16 (4 VGPRs)
typedef __attribute__((ext_vector_type(4))) float f32x4;    // MFMA accumulator

// LDS geometry (shorts). XROW=528 measured 0 bank conflicts (R1/R3/R6).
#define XROW 528
#define XBUF (16 * XROW)     // one 16-t chunk buffer = 8448 shorts (16,896 B)

static __device__ __forceinline__ unsigned short f2bf(float f) {
    union { float f; unsigned u; } v; v.f = f;
    unsigned u = v.u;
    unsigned r = u + 0x7FFFu + ((u >> 16) & 1u);   // round-to-nearest-even
    return (unsigned short)(r >> 16);
}
static __device__ __forceinline__ float fast_exp(float x) {
    return __builtin_amdgcn_exp2f(x * 1.44269504f);
}
static __device__ __forceinline__ float fast_rcp(float x) {
    return __builtin_amdgcn_rcpf(x);
}
// Async global->LDS DMA, 16 B/lane (wave-uniform LDS base + lane*16). R4/R6-verified.
static __device__ __forceinline__ void load_lds16(const unsigned short* g, unsigned short* l) {
    __builtin_amdgcn_global_load_lds(
        (const __attribute__((address_space(1))) unsigned int*)(uintptr_t)g,
        (__attribute__((address_space(3))) unsigned int*)(uintptr_t)l,
        16, 0, 0);
}

// ---------------------------------------------------------------------------
// Pre-kernel: convert sent (T,B,E) and W (3H,E) fp32 -> bf16 in ws (R6-proven).
// ---------------------------------------------------------------------------
__global__ void convert_inputs(const float* __restrict__ X,
                               const float* __restrict__ W,
                               unsigned short* __restrict__ Xb,
                               unsigned short* __restrict__ Wb) {
    const int nX = TT * BB * EE;              // 8,388,608 (divisible by 8)
    int i = (blockIdx.x * blockDim.x + threadIdx.x) * 8;
    const float* src;
    unsigned short* dst;
    int j;
    if (i < nX) { src = X; dst = Xb; j = i; }
    else        { src = W; dst = Wb; j = i - nX; }
    float4 v0 = *(const float4*)(src + j);
    float4 v1 = *(const float4*)(src + j + 4);
    union { short8 s; unsigned short u[8]; } o;
    o.u[0] = f2bf(v0.x); o.u[1] = f2bf(v0.y); o.u[2] = f2bf(v0.z); o.u[3] = f2bf(v0.w);
    o.u[4] = f2bf(v1.x); o.u[5] = f2bf(v1.y); o.u[6] = f2bf(v1.z); o.u[7] = f2bf(v1.w);
    *(short8*)(dst + j) = o.s;
}

// ---------------------------------------------------------------------------
// Fused QRNN, WAVE-SPECIALIZED producer/consumer.
// Block = (batch b, 32 h-cols), 384 threads = 6 waves:
//   waves 0-3: GEMM producers (2 h-tiles x 2 k-halves). W frags in AGPRs,
//              X staged by DMA (double-buffered), 24 MFMAs/chunk, publish
//              RAW partials (both k-halves) to ping-pong exch.
//   waves 4-5: SCAN consumers (one per h-tile). One chunk behind: sum both
//              halves + bias, activations, affine scan, running max, carry.
// R6 post-mortem: block period was the s=0 wave's SERIAL chain (MFMA+tail
// ~1395 cyc) with tails colliding on SIMDs 0/2. Here period = max(GEMM ~550,
// scan ~700): the scan wave's chain overlaps the NEXT chunk's MFMAs on other
// SIMDs, and GEMM waves never carry tails.
// One __syncthreads per chunk. Hazards: publish(ch)->scan-read(ch) separated
// by barrier(ch); exch slot ch&1 reread by scan in iter ch+1, rewritten at
// publish(ch+2) -> barrier(ch+1) separates; X buf: A-read(ch) in iter ch vs
// DMA write(ch+2) in iter ch+1 -> barrier(ch); DMA(ch+1) drained by the
// implicit vmcnt(0) at barrier(ch) before A-read(ch+1).
// exch lane stride 12 floats: b128 access covers all 32 banks per 8 lanes
// (12*8 = 96 = 0 mod 32) -> conflict-free. LDS 58,368 B -> 1 block/CU.
// ---------------------------------------------------------------------------
__launch_bounds__(384, 2)
__global__ void qrnn_fused(const unsigned short* __restrict__ Xb, // bf16 (T,B,E)
                           const unsigned short* __restrict__ Wb, // bf16 (3H,E)
                           const float* __restrict__ bias,        // (3H)
                           float* __restrict__ out)               // (B,H) fp32
{
    __shared__ unsigned short xlds[2 * XBUF];     // 33,792 B
    __shared__ float exch[2][2][2][64][12];       // [slot][hi][s][lane][12] = 24,576 B

    const int tid  = threadIdx.x;
    const int wv   = tid >> 6;         // wave 0..5
    const int lane = tid & 63;
    const int q    = lane >> 4;        // quad 0..3
    const int c    = lane & 15;        // column within 16x16 tile
    const int b    = blockIdx.y;
    const bool isGemm = (wv < 4);
    const int hi   = (wv >> 1) & 1;    // GEMM: h-tile 0..1
    const int s    = wv & 1;           // GEMM: k-half 0..1
    const int shi  = wv - 4;           // SCAN: h-tile 0..1

    // ---- GEMM waves: preload W fragments (k-half s); pin into AGPRs ----
    // B-frag 16x16x32: lane holds n = lane&15 (= h), k = q*8 + j.
    short8 wz[8], wf[8], wo[8];
    if (isGemm) {
        const int h = blockIdx.x * 32 + hi * 16 + c;
        const unsigned short* wzr = Wb + (size_t)h * EE            + s * 256;
        const unsigned short* wfr = Wb + (size_t)(HH + h) * EE     + s * 256;
        const unsigned short* wor = Wb + (size_t)(2 * HH + h) * EE + s * 256;
#pragma unroll
        for (int k = 0; k < 8; ++k) {
            int e0 = k * 32 + q * 8;
            wz[k] = *(const short8*)(wzr + e0);
            wf[k] = *(const short8*)(wfr + e0);
            wo[k] = *(const short8*)(wor + e0);
        }
        // Liveness pin (R3/R4/R6-verified: resident in AGPRs, no spill).
#pragma unroll
        for (int k = 0; k < 8; ++k) {
            asm volatile("" : "+a"(wz[k]), "+a"(wf[k]), "+a"(wo[k]));
        }
    }

    // ---- SCAN waves: bias for their columns ----
    float bz = 0.f, bfg = 0.f, bog = 0.f;
    if (!isGemm) {
        const int h = blockIdx.x * 32 + shi * 16 + c;
        bz  = bias[h];
        bfg = bias[HH + h];
        bog = bias[2 * HH + h];
    }

    float carry = 0.0f;
    float vmax  = -1e30f;

    // ---- staging: GEMM wave wv owns rows wv*4 .. wv*4+3 of each 16-t chunk ----
    const unsigned short* g0 = Xb + ((size_t)((wv & 3) * 4) * BB + b) * EE + lane * 8;
    unsigned short* l0 = &xlds[((wv & 3) * 4) * XROW];
    auto stage = [&](int n, int slot) {
        const unsigned short* g = g0 + (size_t)n * (16 * BB * EE);
        unsigned short* l = l0 + slot * XBUF;
#pragma unroll
        for (int i = 0; i < 4; ++i)
            load_lds16(g + (size_t)i * (BB * EE), l + i * XROW);
    };

    if (isGemm) stage(0, 0);
    __syncthreads();

#pragma unroll 1
    for (int ch = 0; ch <= 32; ++ch) {
        if (isGemm) {
            if (ch < 32) {
                const int buf = ch & 1;
                if (ch < 31) stage(ch + 1, buf ^ 1);

                // A-prefetch: 8 x ds_read_b128 (lane: m=lane&15=t, k=q*8+j)
                const unsigned short* Ab = &xlds[buf * XBUF + c * XROW + s * 256 + q * 8];
                short8 a[8];
#pragma unroll
                for (int k = 0; k < 8; ++k)
                    a[k] = *(const short8*)(Ab + k * 32);

                f32x4 az = {0.f,0.f,0.f,0.f}, af = {0.f,0.f,0.f,0.f}, ao = {0.f,0.f,0.f,0.f};
#pragma unroll
                for (int k = 0; k < 8; ++k) {
                    az = __builtin_amdgcn_mfma_f32_16x16x32_bf16(a[k], wz[k], az, 0, 0, 0);
                    af = __builtin_amdgcn_mfma_f32_16x16x32_bf16(a[k], wf[k], af, 0, 0, 0);
                    ao = __builtin_amdgcn_mfma_f32_16x16x32_bf16(a[k], wo[k], ao, 0, 0, 0);
                }

                // publish raw partials (this k-half) into this chunk's slot
                float* e = &exch[buf][hi][s][lane][0];
                *(f32x4*)(e)     = az;
                *(f32x4*)(e + 4) = af;
                *(f32x4*)(e + 8) = ao;
            }
        } else if (ch > 0) {
            // ---- SCAN: consume chunk ch-1 for tile shi ----
            const int slot = (ch - 1) & 1;
            const float* e0 = &exch[slot][shi][0][lane][0];
            const float* e1 = &exch[slot][shi][1][lane][0];
            f32x4 tz = *(const f32x4*)(e0)     + *(const f32x4*)(e1);
            f32x4 tf = *(const f32x4*)(e0 + 4) + *(const f32x4*)(e1 + 4);
            f32x4 to = *(const f32x4*)(e0 + 8) + *(const f32x4*)(e1 + 8);

            float aa[4], mm[4], oo[4];
#pragma unroll
            for (int r = 0; r < 4; ++r) {
                float yz = tz[r] + bz;
                float yf = tf[r] + bfg;
                float yo = to[r] + bog;
                float e2 = fast_exp(2.0f * yz);
                float z  = 1.0f - 2.0f * fast_rcp(e2 + 1.0f);  // tanh
                float f  = fast_rcp(1.0f + fast_exp(-yf));     // sigmoid
                float o  = fast_rcp(1.0f + fast_exp(-yo));     // sigmoid
                aa[r] = f * z;
                mm[r] = 1.0f - f;
                oo[r] = o;
            }

            // affine scan: compose 4 steps, scan across quads (R6-verified)
            float A = aa[0], M = mm[0];
#pragma unroll
            for (int r = 1; r < 4; ++r) { A = aa[r] + mm[r] * A; M = mm[r] * M; }

            float Ap = __shfl_up(A, 16, 64), Mp = __shfl_up(M, 16, 64);
            if (q >= 1) { A = A + M * Ap; M = M * Mp; }
            Ap = __shfl_up(A, 32, 64); Mp = __shfl_up(M, 32, 64);
            if (q >= 2) { A = A + M * Ap; M = M * Mp; }
            float Ae = __shfl_up(A, 16, 64), Me = __shfl_up(M, 16, 64);
            if (q == 0) { Ae = 0.0f; Me = 1.0f; }
            float cc = Ae + Me * carry;

#pragma unroll
            for (int r = 0; r < 4; ++r) {
                cc = aa[r] + mm[r] * cc;
                vmax = fmaxf(vmax, oo[r] * cc);
            }

            float cend = A + M * carry;
            carry = __shfl(cend, 48 + c, 64);
        }

        __syncthreads();
    }

    if (!isGemm) {
        vmax = fmaxf(vmax, __shfl_xor(vmax, 16, 64));
        vmax = fmaxf(vmax, __shfl_xor(vmax, 32, 64));
        if (q == 0) {
            const int h = blockIdx.x * 32 + shi * 16 + c;
            out[(size_t)b * HH + h] = vmax;
        }
    }
}

// ---------------------------------------------------------------------------
extern "C" void kernel_launch(void* const* d_in, const int* in_sizes, int n_in,
                              void* d_out, int out_size, void* d_ws, size_t ws_size,
                              hipStream_t stream) {
    const float* sent = (const float*)d_in[0];
    // d_in[1] = lengths (unused by the math)
    const float* W    = (const float*)d_in[2];
    const float* bias = (const float*)d_in[3];
    float* out        = (float*)d_out;

    const int nX = TT * BB * EE;        // 8,388,608
    const int nW = 3 * HH * EE;         // 3,145,728
    unsigned short* Xb = (unsigned short*)d_ws;
    unsigned short* Wb = Xb + nX;       // 16 MiB offset, 16B-aligned

    int totalVec = (nX + nW) / 8;       // 1,441,792 threads, exact cover
    convert_inputs<<<totalVec / 256, 256, 0, stream>>>(sent, W, Xb, Wb);

    dim3 grid(HH / 32, BB);             // (64, 32) = 2048 blocks x 384 thr
    qrnn_fused<<<grid, 384, 0, stream>>>(Xb, Wb, bias, out);
}

// Round 11
// 221.552 us; speedup vs baseline: 1.2838x; 1.2838x over previous
//
#include <hip/hip_runtime.h>
#include <stdint.h>

#define TT 512
#define BB 32
#define EE 512
#define HH 2048

typedef __attribute__((ext_vector_type(8))) short short8;   // 8 x bf16 (4 VGPRs)
typedef __attribute__((ext_vector_type(4))) float f32x4;    // MFMA accumulator

// LDS geometry (shorts). XROW=528 measured 0 bank conflicts (R1/R3/R6);
// 520 gave 8.4M conflicts (R4).
#define XROW 528
#define XBUF (16 * XROW)    // one 16-t chunk buffer = 8448 shorts (16.5 KB)

static __device__ __forceinline__ unsigned short f2bf(float f) {
    union { float f; unsigned u; } v; v.f = f;
    unsigned u = v.u;
    unsigned r = u + 0x7FFFu + ((u >> 16) & 1u);   // round-to-nearest-even
    return (unsigned short)(r >> 16);
}
static __device__ __forceinline__ float fast_exp(float x) {
    return __builtin_amdgcn_exp2f(x * 1.44269504f);
}
static __device__ __forceinline__ float fast_rcp(float x) {
    return __builtin_amdgcn_rcpf(x);
}
// Async global->LDS DMA, 16 B/lane (wave-uniform LDS base + lane*16). R4/R6-verified.
static __device__ __forceinline__ void load_lds16(const unsigned short* g, unsigned short* l) {
    __builtin_amdgcn_global_load_lds(
        (const __attribute__((address_space(1))) unsigned int*)(uintptr_t)g,
        (__attribute__((address_space(3))) unsigned int*)(uintptr_t)l,
        16, 0, 0);
}

// ---------------------------------------------------------------------------
// Pre-kernel: convert sent (T,B,E) and W (3H,E) fp32 -> bf16 in ws (R6-proven).
// ---------------------------------------------------------------------------
__global__ void convert_inputs(const float* __restrict__ X,
                               const float* __restrict__ W,
                               unsigned short* __restrict__ Xb,
                               unsigned short* __restrict__ Wb) {
    const int nX = TT * BB * EE;              // 8,388,608 (divisible by 8)
    int i = (blockIdx.x * blockDim.x + threadIdx.x) * 8;
    const float* src;
    unsigned short* dst;
    int j;
    if (i < nX) { src = X; dst = Xb; j = i; }
    else        { src = W; dst = Wb; j = i - nX; }
    float4 v0 = *(const float4*)(src + j);
    float4 v1 = *(const float4*)(src + j + 4);
    union { short8 s; unsigned short u[8]; } o;
    o.u[0] = f2bf(v0.x); o.u[1] = f2bf(v0.y); o.u[2] = f2bf(v0.z); o.u[3] = f2bf(v0.w);
    o.u[4] = f2bf(v1.x); o.u[5] = f2bf(v1.y); o.u[6] = f2bf(v1.z); o.u[7] = f2bf(v1.w);
    *(short8*)(dst + j) = o.s;
}

// ---------------------------------------------------------------------------
// Fused QRNN kernel = R6 (best verified, 149.9us) + 3 blocks/CU.
// Block = (batch b, 32 h-cols), 4 waves = 2 h-tiles x 2 k-halves.
// R10 post-mortem: per-CU chunk period = MFMA contention + exposed tail +
// barrier overhead; the only knob that moved across R6/R9/R10 was number of
// co-resident blocks filling each other's stalls. R6's 46KB LDS already fits
// 3 blocks/CU; registers were the blocker (96 AGPR + 84 arch = 180 > 170).
// Changes vs R6 (numerics untouched):
//   1. __launch_bounds__(256,3): 3 waves/SIMD -> budget 170 regs/wave.
//   2. A-prefetch split 8 -> 4+4: peak live A-frags halve (-16 arch VGPRs),
//      so 96 AGPR + ~70 arch fits 170 without spill.
// ---------------------------------------------------------------------------
__launch_bounds__(256, 3)
__global__ void qrnn_fused(const unsigned short* __restrict__ Xb, // bf16 (T,B,E)
                           const unsigned short* __restrict__ Wb, // bf16 (3H,E)
                           const float* __restrict__ bias,        // (3H)
                           float* __restrict__ out)               // (B,H) fp32
{
    __shared__ unsigned short xlds[2 * XBUF];      // 33,792 B
    __shared__ float exch[2][2][64][12];           // 12,288 B  (total 46,080 B)

    const int tid  = threadIdx.x;
    const int wv   = tid >> 6;         // wave 0..3
    const int lane = tid & 63;
    const int q    = lane >> 4;        // quad 0..3
    const int c    = lane & 15;        // column within 16x16 tile
    const int hi   = wv >> 1;          // h-tile 0..1
    const int s    = wv & 1;           // k-half 0..1
    const int b    = blockIdx.y;
    const int h    = blockIdx.x * 32 + hi * 16 + c;

    // ---- preload W fragments (this wave's K half); pin into AGPRs ----
    // B-frag 16x16x32: lane holds n = lane&15 (= h), k = q*8 + j.
    short8 wz[8], wf[8], wo[8];
    {
        const unsigned short* wzr = Wb + (size_t)h * EE            + s * 256;
        const unsigned short* wfr = Wb + (size_t)(HH + h) * EE     + s * 256;
        const unsigned short* wor = Wb + (size_t)(2 * HH + h) * EE + s * 256;
#pragma unroll
        for (int k = 0; k < 8; ++k) {
            int e0 = k * 32 + q * 8;
            wz[k] = *(const short8*)(wzr + e0);
            wf[k] = *(const short8*)(wfr + e0);
            wo[k] = *(const short8*)(wor + e0);
        }
    }
    // Liveness pin in AGPR class (R3/R4/R6-verified: resident, no spill).
#pragma unroll
    for (int k = 0; k < 8; ++k) {
        asm volatile("" : "+a"(wz[k]), "+a"(wf[k]), "+a"(wo[k]));
    }

    const float b0 = (s == 0) ? bias[h]          : 0.0f;
    const float b1 = (s == 0) ? bias[HH + h]     : 0.0f;
    const float b2 = (s == 0) ? bias[2 * HH + h] : 0.0f;

    float carry = 0.0f;
    float vmax  = -1e30f;

    // ---- staging: wave wv owns rows wv*4 .. wv*4+3 of each 16-t chunk ----
    const unsigned short* g0 = Xb + ((size_t)(wv * 4) * BB + b) * EE + lane * 8;
    unsigned short* l0 = &xlds[(wv * 4) * XROW];
    auto stage = [&](int n, int slot) {
        const unsigned short* g = g0 + (size_t)n * (16 * BB * EE);
        unsigned short* l = l0 + slot * XBUF;
#pragma unroll
        for (int i = 0; i < 4; ++i)
            load_lds16(g + (size_t)i * (BB * EE), l + i * XROW);
    };

    stage(0, 0);
    __syncthreads();

#pragma unroll 1
    for (int ch = 0; ch < 32; ++ch) {
        const int buf = ch & 1;
        if (ch < 31) stage(ch + 1, buf ^ 1);

        // ---- A-prefetch + MFMA, 4+4 split (half the live A-frags vs R6) ----
        // lane holds m = lane&15 (= t within chunk), k = q*8 + j
        const unsigned short* Abase = &xlds[buf * XBUF + c * XROW + s * 256 + q * 8];

        f32x4 az = {b0, b0, b0, b0};
        f32x4 af = {b1, b1, b1, b1};
        f32x4 ao = {b2, b2, b2, b2};

        short8 a[4];
#pragma unroll
        for (int k = 0; k < 4; ++k)
            a[k] = *(const short8*)(Abase + k * 32);
#pragma unroll
        for (int k = 0; k < 4; ++k) {
            az = __builtin_amdgcn_mfma_f32_16x16x32_bf16(a[k], wz[k], az, 0, 0, 0);
            af = __builtin_amdgcn_mfma_f32_16x16x32_bf16(a[k], wf[k], af, 0, 0, 0);
            ao = __builtin_amdgcn_mfma_f32_16x16x32_bf16(a[k], wo[k], ao, 0, 0, 0);
        }
#pragma unroll
        for (int k = 0; k < 4; ++k)
            a[k] = *(const short8*)(Abase + (k + 4) * 32);
#pragma unroll
        for (int k = 0; k < 4; ++k) {
            az = __builtin_amdgcn_mfma_f32_16x16x32_bf16(a[k], wz[k + 4], az, 0, 0, 0);
            af = __builtin_amdgcn_mfma_f32_16x16x32_bf16(a[k], wf[k + 4], af, 0, 0, 0);
            ao = __builtin_amdgcn_mfma_f32_16x16x32_bf16(a[k], wo[k + 4], ao, 0, 0, 0);
        }

        // ---- s=1 publishes partials into this chunk's exch ping-pong slot ----
        const int eb = ch & 1;
        if (s == 1) {
            float* e = &exch[eb][hi][lane][0];
            *(f32x4*)(e)     = az;
            *(f32x4*)(e + 4) = af;
            *(f32x4*)(e + 8) = ao;
        }

        __syncthreads();   // the ONE barrier per chunk (R6-verified hazard walk)

        // ---- s=0 tail (overlaps co-resident blocks on this SIMD) ----
        if (s == 0) {
            const float* e = &exch[eb][hi][lane][0];
            f32x4 pz = *(const f32x4*)(e);
            f32x4 pf = *(const f32x4*)(e + 4);
            f32x4 po = *(const f32x4*)(e + 8);
            az = az + pz; af = af + pf; ao = ao + po;

            float aa[4], mm[4], oo[4];
#pragma unroll
            for (int r = 0; r < 4; ++r) {
                float e2 = fast_exp(2.0f * az[r]);
                float z  = 1.0f - 2.0f * fast_rcp(e2 + 1.0f);  // tanh
                float f  = fast_rcp(1.0f + fast_exp(-af[r]));  // sigmoid
                float o  = fast_rcp(1.0f + fast_exp(-ao[r]));  // sigmoid
                aa[r] = f * z;
                mm[r] = 1.0f - f;
                oo[r] = o;
            }

            // affine scan: compose 4 steps, scan across quads (R6-verified)
            float A = aa[0], M = mm[0];
#pragma unroll
            for (int r = 1; r < 4; ++r) { A = aa[r] + mm[r] * A; M = mm[r] * M; }

            float Ap = __shfl_up(A, 16, 64), Mp = __shfl_up(M, 16, 64);
            if (q >= 1) { A = A + M * Ap; M = M * Mp; }
            Ap = __shfl_up(A, 32, 64); Mp = __shfl_up(M, 32, 64);
            if (q >= 2) { A = A + M * Ap; M = M * Mp; }
            float Ae = __shfl_up(A, 16, 64), Me = __shfl_up(M, 16, 64);
            if (q == 0) { Ae = 0.0f; Me = 1.0f; }
            float cc = Ae + Me * carry;

#pragma unroll
            for (int r = 0; r < 4; ++r) {
                cc = aa[r] + mm[r] * cc;
                vmax = fmaxf(vmax, oo[r] * cc);
            }

            float cend = A + M * carry;
            carry = __shfl(cend, 48 + c, 64);
        }
    }

    if (s == 0) {
        vmax = fmaxf(vmax, __shfl_xor(vmax, 16, 64));
        vmax = fmaxf(vmax, __shfl_xor(vmax, 32, 64));
        if (q == 0) out[(size_t)b * HH + h] = vmax;
    }
}

// ---------------------------------------------------------------------------
extern "C" void kernel_launch(void* const* d_in, const int* in_sizes, int n_in,
                              void* d_out, int out_size, void* d_ws, size_t ws_size,
                              hipStream_t stream) {
    const float* sent = (const float*)d_in[0];
    // d_in[1] = lengths (unused by the math)
    const float* W    = (const float*)d_in[2];
    const float* bias = (const float*)d_in[3];
    float* out        = (float*)d_out;

    const int nX = TT * BB * EE;        // 8,388,608
    const int nW = 3 * HH * EE;         // 3,145,728
    unsigned short* Xb = (unsigned short*)d_ws;
    unsigned short* Wb = Xb + nX;       // 16 MiB offset, 16B-aligned

    int totalVec = (nX + nW) / 8;       // 1,441,792 threads, exact cover
    convert_inputs<<<totalVec / 256, 256, 0, stream>>>(sent, W, Xb, Wb);

    dim3 grid(HH / 32, BB);             // (64, 32) = 2048 blocks
    qrnn_fused<<<grid, 256, 0, stream>>>(Xb, Wb, bias, out);
}